// Round 1
// baseline (503.523 us; speedup 1.0000x reference)
//
#include <hip/hip_runtime.h>

// MSAColumnAttention fused kernels for MI355X (gfx950).
// Shapes: N_SEQ=256, N_RES=256, D=256, H=8, C=32.
//
// ws layout (ushort elements):
//   [0      .. 196608)  qkv_wT  [768][256] bf16  (q rows pre-scaled by C^-0.5)
//   [196608 .. 262144)  gate_wT [256][256] bf16
//   [262144 .. 327680)  out_wT  [256][256] bf16
//   [327680 .. +16.7M)  og      [(r*256+s)][256] bf16  (o * gate)

typedef short bf16x8 __attribute__((ext_vector_type(8)));
typedef float f32x4  __attribute__((ext_vector_type(4)));

union U8 { ushort u[8]; uint w[4]; bf16x8 v; };

__device__ __forceinline__ ushort f2bf(float f) {
  uint u = __float_as_uint(f);
  u = (u + 0x7fffu + ((u >> 16) & 1u)) >> 16;   // RNE
  return (ushort)u;
}

__device__ __forceinline__ f32x4 MFMA(bf16x8 a, bf16x8 b, f32x4 c) {
  return __builtin_amdgcn_mfma_f32_16x16x32_bf16(a, b, c, 0, 0, 0);
}

// Mn tile: smem[0..131072), row s stride 512B, elem (s,d) at s*512 + ((2d)^((s&7)<<4))
__device__ __forceinline__ bf16x8 ldMn(const char* smem, int row, int ko) {
  return *(const bf16x8*)(smem + row * 512 + ((ko * 2) ^ ((row & 7) << 4)));
}
// Global bf16 matrix [*][256], 16B fragment load
__device__ __forceinline__ bf16x8 ldG(const ushort* p, int row, int ko) {
  return *(const bf16x8*)(p + row * 256 + ko);
}
// KV buffer: smem[131072..163840), row stride 128B, cols 0..31 = K (also q/og bounce), 32..63 = V
__device__ __forceinline__ int kvb(int row, int col) {
  return 131072 + row * 128 + ((col * 2) ^ ((row & 7) << 4));
}

__global__ void k_prep(const float* __restrict__ qkv_w, const float* __restrict__ gate_w,
                       const float* __restrict__ out_w, ushort* __restrict__ ws) {
  int idx = blockIdx.x * 256 + threadIdx.x;
  if (idx < 196608) {                       // qkv_wT[col][d] = qkv_w[d][col]
    int col = idx >> 8, d = idx & 255;
    float v = qkv_w[d * 768 + col];
    if (col < 256) v *= 0.17677669529663687f;   // C^-0.5 folded into Wq
    ws[idx] = f2bf(v);
  } else if (idx < 262144) {                // gate_wT[c][d] = gate_w[d][c]
    int i2 = idx - 196608;
    int c = i2 >> 8, d = i2 & 255;
    ws[idx] = f2bf(gate_w[d * 256 + c]);
  } else if (idx < 327680) {                // out_wT[d][hc] = out_w[hc][d]
    int i3 = idx - 262144;
    int d = i3 >> 8, hc = i3 & 255;
    ws[idx] = f2bf(out_w[hc * 256 + d]);
  }
}

__global__ __launch_bounds__(512, 2) void k_attn(
    const float* __restrict__ M_raw, const float* __restrict__ M_mask,
    const float* __restrict__ ln_w, const float* __restrict__ ln_b,
    const ushort* __restrict__ qkv_wT, const ushort* __restrict__ gate_wT,
    const float* __restrict__ gate_b, ushort* __restrict__ og)
{
  extern __shared__ char smem[];
  const int r    = blockIdx.x;
  const int tid  = threadIdx.x;
  const int w    = tid >> 6;      // wave 0..7
  const int lane = tid & 63;
  const int l15  = lane & 15;
  const int g    = lane >> 4;     // 16-lane group 0..3
  const int Q0   = w << 5;        // this wave's 32 s-rows

  // ---------- LayerNorm: rows Q0..Q0+31 -> Mn(bf16, swizzled) ----------
  for (int i = 0; i < 32; ++i) {
    const int s = Q0 + i;
    const float4 x = *(const float4*)(M_raw + (size_t)s * 65536 + (size_t)r * 256 + lane * 4);
    float sum = x.x + x.y + x.z + x.w;
    float sq  = x.x * x.x + x.y * x.y + x.z * x.z + x.w * x.w;
    #pragma unroll
    for (int mk = 1; mk <= 32; mk <<= 1) {
      sum += __shfl_xor(sum, mk, 64);
      sq  += __shfl_xor(sq,  mk, 64);
    }
    const float mu = sum * 0.00390625f;
    const float rs = rsqrtf(sq * 0.00390625f - mu * mu + 1e-5f);
    const float4 wv = *(const float4*)(ln_w + lane * 4);
    const float4 bv = *(const float4*)(ln_b + lane * 4);
    uint2 pk;
    pk.x = (uint)f2bf((x.x - mu) * rs * wv.x + bv.x) | ((uint)f2bf((x.y - mu) * rs * wv.y + bv.y) << 16);
    pk.y = (uint)f2bf((x.z - mu) * rs * wv.z + bv.z) | ((uint)f2bf((x.w - mu) * rs * wv.w + bv.w) << 16);
    *(uint2*)(smem + s * 512 + ((lane * 8) ^ ((s & 7) << 4))) = pk;
  }

  // per-lane mask bits for this lane's k-subset: k = 16*mt + 4*g + rr
  uint mb0 = 0, mb1 = 0;
  for (int i = 0; i < 64; ++i) {
    const int k = ((i >> 2) << 4) + (g << 2) + (i & 3);
    const uint bit = (M_mask[(size_t)k * 256 + r] > 0.5f) ? 1u : 0u;
    if (i < 32) mb0 |= bit << i; else mb1 |= bit << (i - 32);
  }
  __syncthreads();

  const f32x4 Z = {0.f, 0.f, 0.f, 0.f};

  for (int h = 0; h < 8; ++h) {
    const int hs = h << 5;

    // ---------- Q GEMM: q[Q0..Q0+31][0..31] = Mn @ Wq ----------
    f32x4 qa00 = Z, qa01 = Z, qa10 = Z, qa11 = Z;
    #pragma unroll
    for (int kk = 0; kk < 8; ++kk) {
      const int ko = kk * 32 + g * 8;
      const bf16x8 a0 = ldMn(smem, Q0 + l15,      ko);
      const bf16x8 a1 = ldMn(smem, Q0 + 16 + l15, ko);
      const bf16x8 b0 = ldG(qkv_wT, hs + l15,      ko);
      const bf16x8 b1 = ldG(qkv_wT, hs + 16 + l15, ko);
      qa00 = MFMA(a0, b0, qa00);  qa01 = MFMA(a0, b1, qa01);
      qa10 = MFMA(a1, b0, qa10);  qa11 = MFMA(a1, b1, qa11);
    }
    // bounce q through own rows of kv buffer (cols 0..31)
    #pragma unroll
    for (int mt = 0; mt < 2; ++mt)
      #pragma unroll
      for (int nt = 0; nt < 2; ++nt)
        #pragma unroll
        for (int i = 0; i < 4; ++i) {
          const int row = Q0 + mt * 16 + g * 4 + i;
          const int c   = nt * 16 + l15;
          const f32x4 src = mt == 0 ? (nt == 0 ? qa00 : qa01) : (nt == 0 ? qa10 : qa11);
          *(ushort*)(smem + kvb(row, c)) = f2bf(src[i]);
        }
    __syncthreads();                                       // (A) q visible cross-lane
    const bf16x8 bq0 = *(const bf16x8*)(smem + kvb(Q0 + l15,      g * 8));
    const bf16x8 bq1 = *(const bf16x8*)(smem + kvb(Q0 + 16 + l15, g * 8));

    // ---------- K,V GEMMs into own rows ----------
    f32x4 ka00 = Z, ka01 = Z, ka10 = Z, ka11 = Z;
    f32x4 va00 = Z, va01 = Z, va10 = Z, va11 = Z;
    #pragma unroll
    for (int kk = 0; kk < 8; ++kk) {
      const int ko = kk * 32 + g * 8;
      const bf16x8 a0  = ldMn(smem, Q0 + l15,      ko);
      const bf16x8 a1  = ldMn(smem, Q0 + 16 + l15, ko);
      const bf16x8 bk0 = ldG(qkv_wT, 256 + hs + l15,      ko);
      const bf16x8 bk1 = ldG(qkv_wT, 256 + hs + 16 + l15, ko);
      const bf16x8 bv0 = ldG(qkv_wT, 512 + hs + l15,      ko);
      const bf16x8 bv1 = ldG(qkv_wT, 512 + hs + 16 + l15, ko);
      ka00 = MFMA(a0, bk0, ka00);  ka01 = MFMA(a0, bk1, ka01);
      ka10 = MFMA(a1, bk0, ka10);  ka11 = MFMA(a1, bk1, ka11);
      va00 = MFMA(a0, bv0, va00);  va01 = MFMA(a0, bv1, va01);
      va10 = MFMA(a1, bv0, va10);  va11 = MFMA(a1, bv1, va11);
    }
    #pragma unroll
    for (int mt = 0; mt < 2; ++mt)
      #pragma unroll
      for (int nt = 0; nt < 2; ++nt)
        #pragma unroll
        for (int i = 0; i < 4; ++i) {
          const int row = Q0 + mt * 16 + g * 4 + i;
          const int c   = nt * 16 + l15;
          const f32x4 sk = mt == 0 ? (nt == 0 ? ka00 : ka01) : (nt == 0 ? ka10 : ka11);
          const f32x4 sv = mt == 0 ? (nt == 0 ? va00 : va01) : (nt == 0 ? va10 : va11);
          *(ushort*)(smem + kvb(row, c))      = f2bf(sk[i]);
          *(ushort*)(smem + kvb(row, 32 + c)) = f2bf(sv[i]);
        }
    __syncthreads();                                       // (B) K,V staged for all waves

    // ---------- QK^T swapped: S^T[k][q], k=16*mt+4*g+i (rows), q=16*nt+l15 (cols) ----------
    f32x4 S[16][2];
    #pragma unroll
    for (int mt = 0; mt < 16; ++mt) { S[mt][0] = Z; S[mt][1] = Z; }
    #pragma unroll
    for (int mt = 0; mt < 16; ++mt) {
      const bf16x8 ak = *(const bf16x8*)(smem + kvb(mt * 16 + l15, g * 8));
      S[mt][0] = MFMA(ak, bq0, S[mt][0]);
      S[mt][1] = MFMA(ak, bq1, S[mt][1]);
    }

    // ---------- softmax over k (per q column): in-lane 64 vals + shfl_xor 16,32 ----------
    float inv0 = 0.f, inv1 = 0.f;
    #pragma unroll
    for (int nt = 0; nt < 2; ++nt) {
      float mx = -3.0e38f;
      #pragma unroll
      for (int mt = 0; mt < 16; ++mt)
        #pragma unroll
        for (int i = 0; i < 4; ++i) mx = fmaxf(mx, S[mt][nt][i]);
      mx = fmaxf(mx, __shfl_xor(mx, 16, 64));
      mx = fmaxf(mx, __shfl_xor(mx, 32, 64));
      float sum = 0.f;
      #pragma unroll
      for (int mt = 0; mt < 16; ++mt)
        #pragma unroll
        for (int i = 0; i < 4; ++i) {
          float p = __expf(S[mt][nt][i] - mx);
          const int bi = mt * 4 + i;
          const uint bit = (bi < 32) ? (mb0 >> bi) : (mb1 >> (bi - 32));
          p = (bit & 1u) ? p : 0.f;
          S[mt][nt][i] = p;             // unnormalized P
          sum += p;
        }
      sum += __shfl_xor(sum, 16, 64);
      sum += __shfl_xor(sum, 32, 64);
      const float iv = 1.0f / sum;
      if (nt == 0) inv0 = iv; else inv1 = iv;
    }

    // ---------- PV: o^T[c][q] = V^T @ P^T ; B-frags of P^T built via cross-lane shuffles ----------
    f32x4 o00 = Z, o01 = Z, o10 = Z, o11 = Z;
    const int s1 = l15 + ((g & 1) ? 32 : 0);
    const int s2 = s1 + 16;
    const bool hi = (g >= 2);
    #pragma unroll
    for (int kb = 0; kb < 8; ++kb) {
      bf16x8 bp[2];
      #pragma unroll
      for (int nt = 0; nt < 2; ++nt) {
        const uint pa01 = (uint)f2bf(S[2 * kb + 0][nt][0]) | ((uint)f2bf(S[2 * kb + 0][nt][1]) << 16);
        const uint pa23 = (uint)f2bf(S[2 * kb + 0][nt][2]) | ((uint)f2bf(S[2 * kb + 0][nt][3]) << 16);
        const uint pb01 = (uint)f2bf(S[2 * kb + 1][nt][0]) | ((uint)f2bf(S[2 * kb + 1][nt][1]) << 16);
        const uint pb23 = (uint)f2bf(S[2 * kb + 1][nt][2]) | ((uint)f2bf(S[2 * kb + 1][nt][3]) << 16);
        const uint w0a = (uint)__shfl((int)pa01, s1, 64), w0b = (uint)__shfl((int)pb01, s1, 64);
        const uint w1a = (uint)__shfl((int)pa23, s1, 64), w1b = (uint)__shfl((int)pb23, s1, 64);
        const uint w2a = (uint)__shfl((int)pa01, s2, 64), w2b = (uint)__shfl((int)pb01, s2, 64);
        const uint w3a = (uint)__shfl((int)pa23, s2, 64), w3b = (uint)__shfl((int)pb23, s2, 64);
        U8 u;
        u.w[0] = hi ? w0b : w0a;  u.w[1] = hi ? w1b : w1a;
        u.w[2] = hi ? w2b : w2a;  u.w[3] = hi ? w3b : w3a;
        bp[nt] = u.v;
      }
      #pragma unroll
      for (int mtc = 0; mtc < 2; ++mtc) {
        U8 av;
        const int c = mtc * 16 + l15;
        #pragma unroll
        for (int j = 0; j < 8; ++j) {
          const int row = kb * 32 + g * 8 + j;
          av.u[j] = *(const ushort*)(smem + kvb(row, 32 + c));
        }
        if (mtc == 0) { o00 = MFMA(av.v, bp[0], o00); o01 = MFMA(av.v, bp[1], o01); }
        else          { o10 = MFMA(av.v, bp[0], o10); o11 = MFMA(av.v, bp[1], o11); }
      }
    }

    // ---------- gate^T[c][q] = gate_wT(rows hs..) @ Mn^T ----------
    f32x4 ga00 = Z, ga01 = Z, ga10 = Z, ga11 = Z;
    #pragma unroll
    for (int kk = 0; kk < 8; ++kk) {
      const int ko = kk * 32 + g * 8;
      const bf16x8 ag0 = ldG(gate_wT, hs + l15,      ko);
      const bf16x8 ag1 = ldG(gate_wT, hs + 16 + l15, ko);
      const bf16x8 bm0 = ldMn(smem, Q0 + l15,      ko);
      const bf16x8 bm1 = ldMn(smem, Q0 + 16 + l15, ko);
      ga00 = MFMA(ag0, bm0, ga00);  ga01 = MFMA(ag0, bm1, ga01);
      ga10 = MFMA(ag1, bm0, ga10);  ga11 = MFMA(ag1, bm1, ga11);
    }
    __syncthreads();                                       // (C) all K/V reads done

    // ---------- og = o * inv * sigmoid(gate + b) -> bounce into own rows (cols 0..31) ----------
    #pragma unroll
    for (int mtc = 0; mtc < 2; ++mtc)
      #pragma unroll
      for (int nt = 0; nt < 2; ++nt)
        #pragma unroll
        for (int i = 0; i < 4; ++i) {
          const int c = mtc * 16 + g * 4 + i;
          const float gb = gate_b[hs + c];
          const f32x4 gv = mtc == 0 ? (nt == 0 ? ga00 : ga01) : (nt == 0 ? ga10 : ga11);
          const f32x4 ov = mtc == 0 ? (nt == 0 ? o00 : o01)   : (nt == 0 ? o10 : o11);
          const float iv = (nt == 0) ? inv0 : inv1;
          const float sig = 1.0f / (1.0f + __expf(-(gv[i] + gb)));
          const float val = ov[i] * iv * sig;
          const int row = Q0 + nt * 16 + l15;
          *(ushort*)(smem + kvb(row, c)) = f2bf(val);
        }
    __syncthreads();                                       // (D) bounce visible cross-lane

    // readback coalesced and store to global og[(r*256+s)][hs..hs+31]
    #pragma unroll
    for (int i2 = 0; i2 < 8; ++i2) {
      const int row = Q0 + i2 * 4 + g;
      const uint wv = *(const uint*)(smem + 131072 + row * 128 + ((l15 * 4) ^ ((row & 7) << 4)));
      const size_t oi = ((size_t)r * 256 + row) * 256 + hs + l15 * 2;
      *(uint*)(og + oi) = wv;
    }
  }
}

// out[s][r][d] = M_raw[s][r][d] + (og @ out_w)[r*256+s][d] + out_b[d]
__global__ __launch_bounds__(256) void k_out(
    const ushort* __restrict__ og, const ushort* __restrict__ out_wT,
    const float* __restrict__ out_b, const float* __restrict__ M_raw,
    float* __restrict__ out)
{
  const int blk  = blockIdx.x;          // 0..1023, 64 og-rows each
  const int tid  = threadIdx.x;
  const int w    = tid >> 6;
  const int lane = tid & 63;
  const int l15  = lane & 15;
  const int g    = lane >> 4;
  const int row0 = blk * 64 + w * 16;

  const f32x4 Z = {0.f, 0.f, 0.f, 0.f};
  f32x4 acc[16];
  #pragma unroll
  for (int nt = 0; nt < 16; ++nt) acc[nt] = Z;

  #pragma unroll
  for (int kk = 0; kk < 8; ++kk) {
    const bf16x8 a = *(const bf16x8*)(og + (size_t)(row0 + l15) * 256 + kk * 32 + 8 * g);
    #pragma unroll
    for (int nt = 0; nt < 16; ++nt) {
      const bf16x8 b = *(const bf16x8*)(out_wT + (size_t)(nt * 16 + l15) * 256 + kk * 32 + 8 * g);
      acc[nt] = MFMA(a, b, acc[nt]);
    }
  }

  const int r  = row0 >> 8;
  const int s0 = row0 & 255;
  #pragma unroll
  for (int nt = 0; nt < 16; ++nt) {
    const int d = nt * 16 + l15;
    const float ob = out_b[d];
    #pragma unroll
    for (int i = 0; i < 4; ++i) {
      const int s = s0 + 4 * g + i;
      const size_t idx = (size_t)s * 65536 + (size_t)r * 256 + d;
      out[idx] = M_raw[idx] + acc[nt][i] + ob;
    }
  }
}

extern "C" void kernel_launch(void* const* d_in, const int* in_sizes, int n_in,
                              void* d_out, int out_size, void* d_ws, size_t ws_size,
                              hipStream_t stream) {
  const float* M_raw  = (const float*)d_in[0];
  const float* M_mask = (const float*)d_in[1];
  const float* ln_w   = (const float*)d_in[2];
  const float* ln_b   = (const float*)d_in[3];
  const float* qkv_w  = (const float*)d_in[4];
  const float* gate_w = (const float*)d_in[5];
  const float* gate_b = (const float*)d_in[6];
  const float* out_w  = (const float*)d_in[7];
  const float* out_b  = (const float*)d_in[8];

  ushort* ws      = (ushort*)d_ws;
  ushort* qkv_wT  = ws;
  ushort* gate_wT = ws + 196608;
  ushort* out_wT  = ws + 262144;
  ushort* og      = ws + 327680;

  // allow 160KB dynamic LDS (idempotent host-side call; not a stream op)
  hipFuncSetAttribute(reinterpret_cast<const void*>(k_attn),
                      hipFuncAttributeMaxDynamicSharedMemorySize, 163840);

  hipLaunchKernelGGL(k_prep, dim3(1280), dim3(256), 0, stream, qkv_w, gate_w, out_w, ws);
  hipLaunchKernelGGL(k_attn, dim3(256), dim3(512), 163840, stream,
                     M_raw, M_mask, ln_w, ln_b, qkv_wT, gate_wT, gate_b, og);
  hipLaunchKernelGGL(k_out, dim3(1024), dim3(256), 0, stream,
                     og, out_wT, out_b, M_raw, (float*)d_out);
}

// Round 4
// 376.624 us; speedup vs baseline: 1.3369x; 1.3369x over previous
//
#include <hip/hip_runtime.h>

// MSAColumnAttention fused kernels for MI355X (gfx950).
// N_SEQ=256, N_RES=256, D=256, H=8, C=32.
//
// ws layout (ushort elements):
//   [0      .. 196608)  qkv_wT  [768][256] bf16  (q rows pre-scaled by C^-0.5)
//   [196608 .. 262144)  gate_wT [256][256] bf16
//   [262144 .. 327680)  out_wT  [256][256] bf16
//   [327680 .. +16.7M)  og2     [r][h][s][c] bf16  (o * gate, head-major)

typedef short bf16x8 __attribute__((ext_vector_type(8)));
typedef float f32x4  __attribute__((ext_vector_type(4)));

union U8 { uint w[4]; bf16x8 v; ushort u[8]; };

__device__ __forceinline__ ushort f2bf(float f) {
  uint u = __float_as_uint(f);
  u = (u + 0x7fffu + ((u >> 16) & 1u)) >> 16;   // RNE
  return (ushort)u;
}

// pack two floats -> two bf16 in a uint (lo in low half)
__device__ __forceinline__ uint pk2(float lo, float hi) {
  return (uint)f2bf(lo) | ((uint)f2bf(hi) << 16);
}

__device__ __forceinline__ f32x4 MFMA(bf16x8 a, bf16x8 b, f32x4 c) {
  return __builtin_amdgcn_mfma_f32_16x16x32_bf16(a, b, c, 0, 0, 0);
}

// global bf16 matrix [*][256], 16B fragment load
__device__ __forceinline__ bf16x8 ldG(const ushort* __restrict__ p, int row, int ko) {
  return *(const bf16x8*)(p + (size_t)row * 256 + ko);
}

// ---------------- k_prep: LDS-tiled transposes of the 3 weight mats ----------
__global__ __launch_bounds__(256) void k_prep(const float* __restrict__ qkv_w,
                                              const float* __restrict__ gate_w,
                                              const float* __restrict__ out_w,
                                              ushort* __restrict__ ws) {
  __shared__ ushort t[64][72];
  const int b = blockIdx.x;
  const float* src; ushort* dst; int C, r0, c0; bool scale_q = false;
  if (b < 48)      { src = qkv_w;  dst = ws;          C = 768; r0 = (b/12)*64;      c0 = (b%12)*64; scale_q = true; }
  else if (b < 64) { int bb = b-48; src = gate_w; dst = ws + 196608; C = 256; r0 = (bb>>2)*64; c0 = (bb&3)*64; }
  else             { int bb = b-64; src = out_w;  dst = ws + 262144; C = 256; r0 = (bb>>2)*64; c0 = (bb&3)*64; }
  const int tid = threadIdx.x;
  const int cc = tid & 63, rb = tid >> 6;
  #pragma unroll
  for (int j = 0; j < 16; ++j) {
    const int rr = j*4 + rb;
    float v = src[(size_t)(r0+rr)*C + c0 + cc];
    if (scale_q && (c0+cc) < 256) v *= 0.17677669529663687f;
    t[cc][rr] = f2bf(v);
  }
  __syncthreads();
  const int dd = (tid & 31)*2, cb = tid >> 5;
  #pragma unroll
  for (int j = 0; j < 8; ++j) {
    const int c2 = j*8 + cb;
    const uint wv = (uint)t[c2][dd] | ((uint)t[c2][dd+1] << 16);
    *(uint*)(dst + (size_t)(c0+c2)*256 + r0 + dd) = wv;
  }
}

// ---------------- k_attn: fused LN + QKV + attention + gate -------------------
// LDS (dynamic, 80KB):
//   K  dbuf: [0,16384) + [16384,32768)     K[s 256][c 32]  row 64B,  swz ^((s&3)<<4)
//   VT dbuf: [32768,49152) + [49152,65536) VT[c 32][s 256] row 512B, swz ^((c&7)<<4)
//   qog    : [65536,81920)                 [s 256][c 32]   row 64B,  swz ^((s&3)<<4)
__global__ __launch_bounds__(512, 2) void k_attn(
    const float* __restrict__ M_raw, const float* __restrict__ M_mask,
    const float* __restrict__ ln_w, const float* __restrict__ ln_b,
    const ushort* __restrict__ qkv_wT, const ushort* __restrict__ gate_wT,
    const float* __restrict__ gate_b, ushort* __restrict__ og)
{
  extern __shared__ char smem[];
  const int r    = blockIdx.x;
  const int tid  = threadIdx.x;
  const int w    = tid >> 6;
  const int lane = tid & 63;
  const int l15  = lane & 15;
  const int g    = lane >> 4;
  const int Q0   = w << 5;
  const int swz  = (l15 & 3) << 4;          // 64B-row buffers: bits 4-5 only
  const f32x4 Z  = {0.f, 0.f, 0.f, 0.f};

  // ---------- LayerNorm directly into register fragments ----------
  // mn[mt][kk]: lane (l15,g) -> row Q0+mt*16+l15, elems d = kk*32+g*8..+7
  bf16x8 mn[2][8];
  #pragma unroll
  for (int mt = 0; mt < 2; ++mt) {
    const int s = Q0 + mt*16 + l15;
    const float* rowp = M_raw + (size_t)s * 65536 + (size_t)r * 256;
    float4 xa[8], xb[8];
    float sum = 0.f, sq = 0.f;
    #pragma unroll
    for (int kk = 0; kk < 8; ++kk) {
      xa[kk] = *(const float4*)(rowp + kk*32 + g*8);
      xb[kk] = *(const float4*)(rowp + kk*32 + g*8 + 4);
      sum += xa[kk].x + xa[kk].y + xa[kk].z + xa[kk].w
           + xb[kk].x + xb[kk].y + xb[kk].z + xb[kk].w;
      sq  += xa[kk].x*xa[kk].x + xa[kk].y*xa[kk].y + xa[kk].z*xa[kk].z + xa[kk].w*xa[kk].w
           + xb[kk].x*xb[kk].x + xb[kk].y*xb[kk].y + xb[kk].z*xb[kk].z + xb[kk].w*xb[kk].w;
    }
    sum += __shfl_xor(sum, 16, 64);  sum += __shfl_xor(sum, 32, 64);
    sq  += __shfl_xor(sq,  16, 64);  sq  += __shfl_xor(sq,  32, 64);
    const float mu = sum * 0.00390625f;
    const float rs = rsqrtf(sq * 0.00390625f - mu*mu + 1e-5f);
    #pragma unroll
    for (int kk = 0; kk < 8; ++kk) {
      const float4 wa = *(const float4*)(ln_w + kk*32 + g*8);
      const float4 wb = *(const float4*)(ln_w + kk*32 + g*8 + 4);
      const float4 ba = *(const float4*)(ln_b + kk*32 + g*8);
      const float4 bb = *(const float4*)(ln_b + kk*32 + g*8 + 4);
      U8 u;
      u.w[0] = pk2((xa[kk].x-mu)*rs*wa.x+ba.x, (xa[kk].y-mu)*rs*wa.y+ba.y);
      u.w[1] = pk2((xa[kk].z-mu)*rs*wa.z+ba.z, (xa[kk].w-mu)*rs*wa.w+ba.w);
      u.w[2] = pk2((xb[kk].x-mu)*rs*wb.x+bb.x, (xb[kk].y-mu)*rs*wb.y+bb.y);
      u.w[3] = pk2((xb[kk].z-mu)*rs*wb.z+bb.z, (xb[kk].w-mu)*rs*wb.w+bb.w);
      mn[mt][kk] = u.v;
    }
  }

  // per-lane mask bits: bit bi=mt*4+i  <->  k = mt*16 + g*4 + i
  uint mb0 = 0, mb1 = 0;
  for (int i = 0; i < 64; ++i) {
    const int k = ((i >> 2) << 4) + (g << 2) + (i & 3);
    const uint bit = (M_mask[(size_t)k * 256 + r] > 0.5f) ? 1u : 0u;
    if (i < 32) mb0 |= bit << i; else mb1 |= bit << (i - 32);
  }

  // swapped projection: acc[mtc][nts] = X^T[c=mtc*16+g*4+i][s=Q0+nts*16+l15]
  auto projT = [&](const ushort* __restrict__ W, int rowbase, f32x4 (&acc)[2][2]) {
    #pragma unroll
    for (int mtc = 0; mtc < 2; ++mtc) {
      #pragma unroll
      for (int kk = 0; kk < 8; ++kk) {
        const bf16x8 a = ldG(W, rowbase + mtc*16 + l15, kk*32 + g*8);
        acc[mtc][0] = MFMA(a, mn[0][kk], acc[mtc][0]);
        acc[mtc][1] = MFMA(a, mn[1][kk], acc[mtc][1]);
      }
    }
  };
  // normal projection: acc[mt][ntc] = V[s=Q0+mt*16+g*4+i][c=ntc*16+l15]
  auto projV = [&](const ushort* __restrict__ W, int rowbase, f32x4 (&acc)[2][2]) {
    #pragma unroll
    for (int ntc = 0; ntc < 2; ++ntc) {
      #pragma unroll
      for (int kk = 0; kk < 8; ++kk) {
        const bf16x8 bfr = ldG(W, rowbase + ntc*16 + l15, kk*32 + g*8);
        acc[0][ntc] = MFMA(mn[0][kk], bfr, acc[0][ntc]);
        acc[1][ntc] = MFMA(mn[1][kk], bfr, acc[1][ntc]);
      }
    }
  };

  // prologue: K^T,V for head 0
  f32x4 kaT[2][2] = {{Z,Z},{Z,Z}}, vaN[2][2] = {{Z,Z},{Z,Z}};
  projT(qkv_wT, 256 + 0, kaT);
  projV(qkv_wT, 512 + 0, vaN);

  for (int h = 0; h < 8; ++h) {
    const int hs = h << 5;
    const int kO = (h & 1) * 16384;
    const int vO = 32768 + (h & 1) * 16384;

    // ---- stage K (rows s, own rows) ----
    #pragma unroll
    for (int mtc = 0; mtc < 2; ++mtc)
      #pragma unroll
      for (int nts = 0; nts < 2; ++nts) {
        uint2 p2; p2.x = pk2(kaT[mtc][nts][0], kaT[mtc][nts][1]);
                  p2.y = pk2(kaT[mtc][nts][2], kaT[mtc][nts][3]);
        const int s = Q0 + nts*16 + l15;
        *(uint2*)(smem + kO + s*64 + ((mtc*32 + g*8) ^ swz)) = p2;
      }
    // ---- stage VT (rows c, own s-segment) ----
    #pragma unroll
    for (int mt = 0; mt < 2; ++mt)
      #pragma unroll
      for (int ntc = 0; ntc < 2; ++ntc) {
        uint2 p2; p2.x = pk2(vaN[mt][ntc][0], vaN[mt][ntc][1]);
                  p2.y = pk2(vaN[mt][ntc][2], vaN[mt][ntc][3]);
        const int c = ntc*16 + l15;
        *(uint2*)(smem + vO + c*512 + (((Q0 + mt*16 + g*4)*2) ^ ((c & 7) << 4))) = p2;
      }

    // ---- q projection + bounce ----
    f32x4 qaT[2][2] = {{Z,Z},{Z,Z}};
    projT(qkv_wT, hs, qaT);
    #pragma unroll
    for (int mtc = 0; mtc < 2; ++mtc)
      #pragma unroll
      for (int nts = 0; nts < 2; ++nts) {
        uint2 p2; p2.x = pk2(qaT[mtc][nts][0], qaT[mtc][nts][1]);
                  p2.y = pk2(qaT[mtc][nts][2], qaT[mtc][nts][3]);
        const int s = Q0 + nts*16 + l15;
        *(uint2*)(smem + 65536 + s*64 + ((mtc*32 + g*8) ^ swz)) = p2;
      }
    __syncthreads();   // (A) q-bounce visible
    const bf16x8 bq0 = *(const bf16x8*)(smem + 65536 + (Q0 + l15)*64      + ((g*16) ^ swz));
    const bf16x8 bq1 = *(const bf16x8*)(smem + 65536 + (Q0 + 16 + l15)*64 + ((g*16) ^ swz));

    __syncthreads();   // (B) K,VT of head h staged by all waves

    // ---- QK^T swapped: S[kt][nt] = S^T[k=kt*16+g*4+i][q=Q0+nt*16+l15] ----
    f32x4 S[16][2];
    #pragma unroll
    for (int mt = 0; mt < 16; ++mt) { S[mt][0] = Z; S[mt][1] = Z; }
    #pragma unroll
    for (int kt = 0; kt < 16; ++kt) {
      const bf16x8 ak = *(const bf16x8*)(smem + kO + (kt*16 + l15)*64 + ((g*16) ^ swz));
      S[kt][0] = MFMA(ak, bq0, S[kt][0]);
      S[kt][1] = MFMA(ak, bq1, S[kt][1]);
    }

    // ---- softmax over k + pack P to bf16 ----
    float inv0 = 0.f, inv1 = 0.f;
    uint pkk[2][16][2];
    #pragma unroll
    for (int nt = 0; nt < 2; ++nt) {
      float mx = -3.0e38f;
      #pragma unroll
      for (int mt = 0; mt < 16; ++mt)
        #pragma unroll
        for (int i = 0; i < 4; ++i) mx = fmaxf(mx, S[mt][nt][i]);
      mx = fmaxf(mx, __shfl_xor(mx, 16, 64));
      mx = fmaxf(mx, __shfl_xor(mx, 32, 64));
      float sum = 0.f;
      #pragma unroll
      for (int mt = 0; mt < 16; ++mt)
        #pragma unroll
        for (int i = 0; i < 4; ++i) {
          float p = __expf(S[mt][nt][i] - mx);
          const int bi = mt*4 + i;
          const uint bit = (bi < 32) ? (mb0 >> bi) : (mb1 >> (bi - 32));
          p = (bit & 1u) ? p : 0.f;
          S[mt][nt][i] = p;
          sum += p;
        }
      sum += __shfl_xor(sum, 16, 64);
      sum += __shfl_xor(sum, 32, 64);
      const float iv = 1.0f / sum;
      if (nt == 0) inv0 = iv; else inv1 = iv;
      #pragma unroll
      for (int mt = 0; mt < 16; ++mt) {
        pkk[nt][mt][0] = pk2(S[mt][nt][0], S[mt][nt][1]);
        pkk[nt][mt][1] = pk2(S[mt][nt][2], S[mt][nt][3]);
      }
    }

    // ---- PV: o^T[c][q] = V^T @ P^T; VT frags b128, P frags via shuffles ----
    f32x4 oA[2][2] = {{Z,Z},{Z,Z}};
    const int srcA = l15 + 32*(g & 1);
    const int srcB = srcA + 16;
    const bool hi = (g >= 2);
    #pragma unroll
    for (int kb = 0; kb < 8; ++kb) {
      U8 bp[2];
      #pragma unroll
      for (int nt = 0; nt < 2; ++nt) {
        const uint a0 = __shfl(pkk[nt][2*kb][0],   srcA), b0 = __shfl(pkk[nt][2*kb+1][0], srcA);
        const uint a1 = __shfl(pkk[nt][2*kb][1],   srcA), b1 = __shfl(pkk[nt][2*kb+1][1], srcA);
        const uint a2 = __shfl(pkk[nt][2*kb][0],   srcB), b2 = __shfl(pkk[nt][2*kb+1][0], srcB);
        const uint a3 = __shfl(pkk[nt][2*kb][1],   srcB), b3 = __shfl(pkk[nt][2*kb+1][1], srcB);
        bp[nt].w[0] = hi ? b0 : a0;  bp[nt].w[1] = hi ? b1 : a1;
        bp[nt].w[2] = hi ? b2 : a2;  bp[nt].w[3] = hi ? b3 : a3;
      }
      #pragma unroll
      for (int mtc = 0; mtc < 2; ++mtc) {
        const int c = mtc*16 + l15;
        const bf16x8 av = *(const bf16x8*)(smem + vO + c*512 + ((kb*64 + g*16) ^ ((c & 7) << 4)));
        oA[mtc][0] = MFMA(av, bp[0].v, oA[mtc][0]);
        oA[mtc][1] = MFMA(av, bp[1].v, oA[mtc][1]);
      }
    }

    // ---- K^T,V for next head ----
    if (h < 7) {
      #pragma unroll
      for (int a = 0; a < 2; ++a)
        #pragma unroll
        for (int bb = 0; bb < 2; ++bb) { kaT[a][bb] = Z; vaN[a][bb] = Z; }
      projT(qkv_wT, 256 + hs + 32, kaT);
      projV(qkv_wT, 512 + hs + 32, vaN);
    }

    // ---- gate (same layout as oA) + combine + og bounce ----
    f32x4 gaT[2][2] = {{Z,Z},{Z,Z}};
    projT(gate_wT, hs, gaT);
    #pragma unroll
    for (int mtc = 0; mtc < 2; ++mtc)
      #pragma unroll
      for (int nt = 0; nt < 2; ++nt) {
        float vals[4];
        #pragma unroll
        for (int i = 0; i < 4; ++i) {
          const float gb  = gate_b[hs + mtc*16 + g*4 + i];
          const float sig = 1.0f / (1.0f + __expf(-(gaT[mtc][nt][i] + gb)));
          vals[i] = oA[mtc][nt][i] * (nt ? inv1 : inv0) * sig;
        }
        uint2 p2; p2.x = pk2(vals[0], vals[1]); p2.y = pk2(vals[2], vals[3]);
        const int s = Q0 + nt*16 + l15;
        *(uint2*)(smem + 65536 + s*64 + ((mtc*32 + g*8) ^ swz)) = p2;
      }
    __syncthreads();   // (D) og-bounce visible
    // own-rows readback -> contiguous 256B global stores
    uint* ogw = (uint*)og;
    const size_t ob = ((size_t)(r*8 + h) * 256) * 16;   // uint units
    #pragma unroll
    for (int j2 = 0; j2 < 8; ++j2) {
      const int lin = j2*64 + lane;
      const int row = Q0 + (lin >> 4);
      const int cu  = lin & 15;
      const uint wv = *(const uint*)(smem + 65536 + row*64 + ((cu*4) ^ ((row & 3) << 4)));
      ogw[ob + (size_t)row*16 + cu] = wv;
    }
  }
}

// ---------------- k_out: out[s][r][d] = M_raw + og2 @ out_w + out_b ----------
__global__ __launch_bounds__(256) void k_out(
    const ushort* __restrict__ og, const ushort* __restrict__ out_wT,
    const float* __restrict__ out_b, const float* __restrict__ M_raw,
    float* __restrict__ out)
{
  const int blk  = blockIdx.x;
  const int tid  = threadIdx.x;
  const int w    = tid >> 6;
  const int lane = tid & 63;
  const int l15  = lane & 15;
  const int g    = lane >> 4;
  const int row0 = blk * 64 + w * 16;
  const int r    = row0 >> 8;
  const int s0   = row0 & 255;

  const f32x4 Z = {0.f, 0.f, 0.f, 0.f};
  f32x4 acc[16];
  #pragma unroll
  for (int nt = 0; nt < 16; ++nt) acc[nt] = Z;

  #pragma unroll
  for (int kk = 0; kk < 8; ++kk) {   // kk == head
    const bf16x8 a = *(const bf16x8*)(og + ((size_t)(r*8 + kk)*256 + s0 + l15)*32 + g*8);
    #pragma unroll
    for (int nt = 0; nt < 16; ++nt) {
      const bf16x8 b = ldG(out_wT, nt*16 + l15, kk*32 + g*8);
      acc[nt] = MFMA(a, b, acc[nt]);
    }
  }

  #pragma unroll
  for (int nt = 0; nt < 16; ++nt) {
    const int d = nt*16 + l15;
    const float ob = out_b[d];
    #pragma unroll
    for (int i = 0; i < 4; ++i) {
      const int s = s0 + 4*g + i;
      const size_t idx = (size_t)s * 65536 + (size_t)r * 256 + d;
      out[idx] = M_raw[idx] + acc[nt][i] + ob;
    }
  }
}

extern "C" void kernel_launch(void* const* d_in, const int* in_sizes, int n_in,
                              void* d_out, int out_size, void* d_ws, size_t ws_size,
                              hipStream_t stream) {
  const float* M_raw  = (const float*)d_in[0];
  const float* M_mask = (const float*)d_in[1];
  const float* ln_w   = (const float*)d_in[2];
  const float* ln_b   = (const float*)d_in[3];
  const float* qkv_w  = (const float*)d_in[4];
  const float* gate_w = (const float*)d_in[5];
  const float* gate_b = (const float*)d_in[6];
  const float* out_w  = (const float*)d_in[7];
  const float* out_b  = (const float*)d_in[8];

  ushort* ws      = (ushort*)d_ws;
  ushort* qkv_wT  = ws;
  ushort* gate_wT = ws + 196608;
  ushort* out_wT  = ws + 262144;
  ushort* og      = ws + 327680;

  hipFuncSetAttribute(reinterpret_cast<const void*>(k_attn),
                      hipFuncAttributeMaxDynamicSharedMemorySize, 81920);

  hipLaunchKernelGGL(k_prep, dim3(80), dim3(256), 0, stream, qkv_w, gate_w, out_w, ws);
  hipLaunchKernelGGL(k_attn, dim3(256), dim3(512), 81920, stream,
                     M_raw, M_mask, ln_w, ln_b, qkv_wT, gate_wT, gate_b, og);
  hipLaunchKernelGGL(k_out, dim3(1024), dim3(256), 0, stream,
                     og, out_wT, out_b, M_raw, (float*)d_out);
}